// Round 1
// 3516.749 us; speedup vs baseline: 1.7935x; 1.7935x over previous
//
#include <hip/hip_runtime.h>
#include <hip/hip_fp16.h>

#define TT 512
#define BB 256
#define OBS 128
#define LAT 64
#define HID 256

typedef short bvec8 __attribute__((ext_vector_type(8)));
typedef float fvec4 __attribute__((ext_vector_type(4)));

__device__ __forceinline__ short f2bf(float f){
  union { float f; unsigned u; } v; v.f = f;
  unsigned u = v.u;
  return (short)((u + 0x7FFFu + ((u >> 16) & 1u)) >> 16);
}

__device__ __forceinline__ bvec8 cvt8(const float* __restrict__ p){
  const float4* q = (const float4*)p;
  float4 lo = q[0], hi = q[1];
  bvec8 r;
  r[0] = f2bf(lo.x); r[1] = f2bf(lo.y); r[2] = f2bf(lo.z); r[3] = f2bf(lo.w);
  r[4] = f2bf(hi.x); r[5] = f2bf(hi.y); r[6] = f2bf(hi.z); r[7] = f2bf(hi.w);
  return r;
}

__device__ __forceinline__ fvec4 mfma16(bvec8 a, bvec8 b, fvec4 c){
  return __builtin_amdgcn_mfma_f32_16x16x32_bf16(a, b, c, 0, 0, 0);
}

__global__ void cvt_kernel(const float* __restrict__ src, short* __restrict__ dst, int n){
  int i = blockIdx.x * 256 + threadIdx.x;
  if (i < n) dst[i] = f2bf(src[i]);
}

// ---------------------------------------------------------------------------
// gx precompute: gx[t*B+b][gcol] = x[t][b] @ W_ih[gcol]^T + b_ih[gcol]
//                                  + (gcol < 2*HID ? b_hh[gcol] : 0)
// Stored f16 into d_out scratch (exact size match). Massively parallel:
// 2048 wgs x 256 thr; wave handles 16 rows x 768 cols.
// ---------------------------------------------------------------------------
__global__ __launch_bounds__(256) void gx_kernel(
    const float* __restrict__ x, const short* __restrict__ Wih_bf,
    const float* __restrict__ b_ih, const float* __restrict__ b_hh,
    __half* __restrict__ gx)
{
  const int tid  = threadIdx.x;
  const int wave = tid >> 6;
  const int lane = tid & 63;
  const int quad = lane >> 4;
  const int nl   = lane & 15;
  const int rowbase = blockIdx.x * 64 + wave * 16;

  // A-frags for 16 rows of x (K=128), converted to bf16 once, reused 48x
  bvec8 af[4];
#pragma unroll
  for (int ks = 0; ks < 4; ++ks)
    af[ks] = cvt8(x + (size_t)(rowbase + nl)*OBS + ks*32 + quad*8);

  for (int nt = 0; nt < 48; ++nt){
    const int n = nt*16 + nl;
    fvec4 acc = (fvec4)0.0f;
#pragma unroll
    for (int ks = 0; ks < 4; ++ks){
      bvec8 bw = *(const bvec8*)(Wih_bf + (size_t)n*OBS + ks*32 + quad*8);
      acc = mfma16(af[ks], bw, acc);
    }
    float bias = b_ih[n] + (n < 2*HID ? b_hh[n] : 0.0f);
#pragma unroll
    for (int r = 0; r < 4; ++r)
      gx[(size_t)(rowbase + quad*4 + r)*768 + n] = __float2half(acc[r] + bias);
  }
}

// ---------------------------------------------------------------------------
// GRU scan: 16 wgs x 512 threads; wg g owns samples [16g, 16g+16).
// Wave w (0..7) owns gate-columns j in [32w, 32w+32) of each gate (r,z,n).
// W_hh B-frags: r,z + 6 K-slices of n in VGPRs (176), last 2 K-slices of n
// in LDS (32 KB). x-path precomputed (gx, f16), prefetched 1 step ahead.
// __launch_bounds__(512,1): 256-VGPR cap -> no spills (the (512,2) cap of
// 128 VGPRs was spilling ~240 regs of weights to scratch every step).
// ---------------------------------------------------------------------------
__global__ __launch_bounds__(512, 1) void gru_kernel(
    const __half* __restrict__ gx,
    const short* __restrict__ Whh_bf,
    const float* __restrict__ b_hh,
    short* __restrict__ h_all)
{
  const int tid  = threadIdx.x;
  const int wave = tid >> 6;
  const int lane = tid & 63;
  const int quad = lane >> 4;
  const int nl   = lane & 15;
  const int b0   = blockIdx.x * 16;

  __shared__ __align__(16) short hA[2][16][264];
  __shared__ __align__(16) short WnL[2][2][8][512];  // [ks-6][nt][wave][lane*8]

  // ---- weights into registers (B-frag layout: n=nl, k=quad*8+idx) ----
  bvec8 Whr[8][2], Whz[8][2], Whn[6][2];
  float bnh[2];
#pragma unroll
  for (int nt = 0; nt < 2; ++nt){
    const int j = wave*32 + nt*16 + nl;
#pragma unroll
    for (int ks = 0; ks < 8; ++ks){
      Whr[ks][nt] = *(const bvec8*)(Whh_bf + ((size_t)(0*HID + j))*HID + ks*32 + quad*8);
      Whz[ks][nt] = *(const bvec8*)(Whh_bf + ((size_t)(1*HID + j))*HID + ks*32 + quad*8);
    }
#pragma unroll
    for (int ks = 0; ks < 6; ++ks)
      Whn[ks][nt] = *(const bvec8*)(Whh_bf + ((size_t)(2*HID + j))*HID + ks*32 + quad*8);
#pragma unroll
    for (int ks6 = 0; ks6 < 2; ++ks6){
      bvec8 w = *(const bvec8*)(Whh_bf + ((size_t)(2*HID + j))*HID + (6+ks6)*32 + quad*8);
      *(bvec8*)&WnL[ks6][nt][wave][lane*8] = w;
    }
    bnh[nt] = b_hh[2*HID + j];
  }

  float hreg[2][4];
#pragma unroll
  for (int nt = 0; nt < 2; ++nt)
#pragma unroll
    for (int r = 0; r < 4; ++r) hreg[nt][r] = 0.0f;

  // prefetch gx for step 0 (all 3 gates)
  __half gxp[3][2][4];
  {
    const __half* gp = gx + ((size_t)0*BB + b0)*768;
#pragma unroll
    for (int g = 0; g < 3; ++g)
#pragma unroll
      for (int nt = 0; nt < 2; ++nt)
#pragma unroll
        for (int r = 0; r < 4; ++r)
          gxp[g][nt][r] = gp[(size_t)(quad*4+r)*768 + g*HID + wave*32 + nt*16 + nl];
  }

  const int orow = tid >> 5;    // 0..15
  const int oseg = tid & 31;    // 0..31
  __syncthreads();

  for (int i = 0; i < TT; ++i){
    // write out h_{i-1} (coalesced, from LDS buffer finalized last step)
    if (i > 0){
      bvec8 v = *(const bvec8*)&hA[i&1][orow][oseg*8];
      *(bvec8*)(h_all + ((size_t)(i-1)*BB + b0 + orow)*HID + oseg*8) = v;
    }

    // init accumulators from prefetched gx (r,z); n-gate h-part starts at 0
    fvec4 ar[2], az[2], anh_[2];
#pragma unroll
    for (int nt = 0; nt < 2; ++nt){
#pragma unroll
      for (int r = 0; r < 4; ++r){
        ar[nt][r] = __half2float(gxp[0][nt][r]);
        az[nt][r] = __half2float(gxp[1][nt][r]);
      }
      anh_[nt] = (fvec4)0.0f;
    }

    // prefetch r,z gx for next step (full step of latency cover)
    if (i + 1 < TT){
      const __half* gp = gx + ((size_t)(i+1)*BB + b0)*768;
#pragma unroll
      for (int g = 0; g < 2; ++g)
#pragma unroll
        for (int nt = 0; nt < 2; ++nt)
#pragma unroll
          for (int r = 0; r < 4; ++r)
            gxp[g][nt][r] = gp[(size_t)(quad*4+r)*768 + g*HID + wave*32 + nt*16 + nl];
    }

    // h-part MFMAs (K=256)
    if (i > 0){
#pragma unroll
      for (int ks = 0; ks < 8; ++ks){
        bvec8 a = *(const bvec8*)&hA[i&1][nl][ks*32 + quad*8];
#pragma unroll
        for (int nt = 0; nt < 2; ++nt){
          ar[nt] = mfma16(a, Whr[ks][nt], ar[nt]);
          az[nt] = mfma16(a, Whz[ks][nt], az[nt]);
          if (ks < 6){
            anh_[nt] = mfma16(a, Whn[ks][nt], anh_[nt]);
          } else {
            bvec8 w = *(const bvec8*)&WnL[ks-6][nt][wave][lane*8];
            anh_[nt] = mfma16(a, w, anh_[nt]);
          }
        }
      }
    }

    // gate math (C-layout: m = quad*4+r, j = wave*32 + nt*16 + nl)
#pragma unroll
    for (int nt = 0; nt < 2; ++nt){
      const int j = wave*32 + nt*16 + nl;
#pragma unroll
      for (int r = 0; r < 4; ++r){
        float rg = 1.0f/(1.0f + __expf(-ar[nt][r]));
        float zg = 1.0f/(1.0f + __expf(-az[nt][r]));
        float ng = tanhf(__half2float(gxp[2][nt][r]) + rg*(anh_[nt][r] + bnh[nt]));
        float hn = (1.0f - zg)*ng + zg*hreg[nt][r];
        hreg[nt][r] = hn;
        hA[(i+1)&1][quad*4 + r][j] = f2bf(hn);
      }
    }

    // prefetch n-gate gx for next step (after its last use this step)
    if (i + 1 < TT){
      const __half* gp = gx + ((size_t)(i+1)*BB + b0)*768;
#pragma unroll
      for (int nt = 0; nt < 2; ++nt)
#pragma unroll
        for (int r = 0; r < 4; ++r)
          gxp[2][nt][r] = gp[(size_t)(quad*4+r)*768 + 2*HID + wave*32 + nt*16 + nl];
    }
    __syncthreads();
  }
  // epilogue: write h_{TT-1}  (TT even -> buffer 0)
  {
    bvec8 v = *(const bvec8*)&hA[TT&1][orow][oseg*8];
    *(bvec8*)(h_all + ((size_t)(TT-1)*BB + b0 + orow)*HID + oseg*8) = v;
  }
}

// ---------------------------------------------------------------------------
// z scan: 16 wgs x 256 threads; wg g owns samples [16g, 16g+16).
// ---------------------------------------------------------------------------
__global__ __launch_bounds__(256, 1) void zscan_kernel(
    const short* __restrict__ h_all, const float* __restrict__ eps,
    const short* __restrict__ Pw1, const short* __restrict__ Pw2,
    const float* __restrict__ pb1, const float* __restrict__ pb2,
    short* __restrict__ z_all,
    float* __restrict__ post_mean, float* __restrict__ post_logvar)
{
  const int tid  = threadIdx.x;
  const int wave = tid >> 6;
  const int lane = tid & 63;
  const int quad = lane >> 4;
  const int nl   = lane & 15;
  const int b0   = blockIdx.x * 16;

  __shared__ __align__(16) short zA[2][16][72];
  __shared__ __align__(16) short uA[16][264];
  __shared__ float postL[16][132];

  // weights (B-frag layout). pW1 is [256][320]: k<256 = h-part, k>=256 = z-part.
  bvec8 W1h[8][4], W1z[2][4], W2[8][2];
  float pb1r[4];
#pragma unroll
  for (int nt = 0; nt < 4; ++nt){
    const int n = wave*64 + nt*16 + nl;
#pragma unroll
    for (int ks = 0; ks < 8; ++ks)
      W1h[ks][nt] = *(const bvec8*)(Pw1 + n*320 + ks*32 + quad*8);
#pragma unroll
    for (int ks = 0; ks < 2; ++ks)
      W1z[ks][nt] = *(const bvec8*)(Pw1 + n*320 + 256 + ks*32 + quad*8);
    pb1r[nt] = pb1[n];
  }
#pragma unroll
  for (int nt = 0; nt < 2; ++nt){
    const int n = wave*32 + nt*16 + nl;
#pragma unroll
    for (int ks = 0; ks < 8; ++ks)
      W2[ks][nt] = *(const bvec8*)(Pw2 + n*HID + ks*32 + quad*8);
  }

  // z-math constants per thread (4 latent cols each)
  const int zm  = tid >> 4;         // sample row 0..15
  const int zl  = (tid & 15) * 4;   // latent col base
  float4 pb2m = *(const float4*)(pb2 + zl);
  float4 pb2v = *(const float4*)(pb2 + 64 + zl);

  // prefetch h-frags + eps for step 0
  bvec8 hf[8];
#pragma unroll
  for (int ks = 0; ks < 8; ++ks)
    hf[ks] = *(const bvec8*)(h_all + ((size_t)0*BB + b0 + nl)*HID + ks*32 + quad*8);
  float4 ef = *(const float4*)(eps + ((size_t)0*BB + b0 + zm)*LAT + zl);

  for (int i = 0; i < TT; ++i){
    // ---- stage pin: u accumulation ----
    fvec4 au[4];
#pragma unroll
    for (int nt = 0; nt < 4; ++nt) au[nt] = (fvec4)0.0f;
#pragma unroll
    for (int ks = 0; ks < 8; ++ks){
      bvec8 a = hf[ks];
#pragma unroll
      for (int nt = 0; nt < 4; ++nt) au[nt] = mfma16(a, W1h[ks][nt], au[nt]);
    }
    if (i > 0){
#pragma unroll
      for (int ks = 0; ks < 2; ++ks){
        bvec8 a = *(const bvec8*)&zA[i&1][nl][ks*32 + quad*8];
#pragma unroll
        for (int nt = 0; nt < 4; ++nt) au[nt] = mfma16(a, W1z[ks][nt], au[nt]);
      }
    }
    // prefetch h for next step
    if (i + 1 < TT){
#pragma unroll
      for (int ks = 0; ks < 8; ++ks)
        hf[ks] = *(const bvec8*)(h_all + ((size_t)(i+1)*BB + b0 + nl)*HID + ks*32 + quad*8);
    }
    // u = relu(au + pb1) -> uA
#pragma unroll
    for (int nt = 0; nt < 4; ++nt){
      const int n = wave*64 + nt*16 + nl;
#pragma unroll
      for (int r = 0; r < 4; ++r){
        float u = au[nt][r] + pb1r[nt];
        uA[quad*4 + r][n] = f2bf(u > 0.0f ? u : 0.0f);
      }
    }
    __syncthreads();

    // ---- stage B: post = u @ pW2^T ----
    fvec4 ap[2];
#pragma unroll
    for (int nt = 0; nt < 2; ++nt) ap[nt] = (fvec4)0.0f;
#pragma unroll
    for (int ks = 0; ks < 8; ++ks){
      bvec8 a = *(const bvec8*)&uA[nl][ks*32 + quad*8];
#pragma unroll
      for (int nt = 0; nt < 2; ++nt) ap[nt] = mfma16(a, W2[ks][nt], ap[nt]);
    }
#pragma unroll
    for (int nt = 0; nt < 2; ++nt){
      const int n = wave*32 + nt*16 + nl;
#pragma unroll
      for (int r = 0; r < 4; ++r) postL[quad*4 + r][n] = ap[nt][r];
    }
    __syncthreads();

    // ---- z math ----
    {
      float4 mean, lv;
      mean.x = postL[zm][zl+0] + pb2m.x;  lv.x = postL[zm][64+zl+0] + pb2v.x;
      mean.y = postL[zm][zl+1] + pb2m.y;  lv.y = postL[zm][64+zl+1] + pb2v.y;
      mean.z = postL[zm][zl+2] + pb2m.z;  lv.z = postL[zm][64+zl+2] + pb2v.z;
      mean.w = postL[zm][zl+3] + pb2m.w;  lv.w = postL[zm][64+zl+3] + pb2v.w;
      float z0 = mean.x + ef.x * __expf(0.5f*lv.x);
      float z1 = mean.y + ef.y * __expf(0.5f*lv.y);
      float z2 = mean.z + ef.z * __expf(0.5f*lv.z);
      float z3 = mean.w + ef.w * __expf(0.5f*lv.w);
      size_t orow = ((size_t)i*BB + b0 + zm)*LAT + zl;
      short4 zb; zb.x = f2bf(z0); zb.y = f2bf(z1); zb.z = f2bf(z2); zb.w = f2bf(z3);
      *(short4*)(z_all + orow) = zb;
      *(float4*)(post_mean + orow)   = mean;
      *(float4*)(post_logvar + orow) = lv;
      *(short4*)&zA[(i+1)&1][zm][zl] = zb;
      if (i + 1 < TT)
        ef = *(const float4*)(eps + ((size_t)(i+1)*BB + b0 + zm)*LAT + zl);
    }
    __syncthreads();
  }
}

// ---------------------------------------------------------------------------
// Tail: prior (from z_{t-1}) and decoder (from z_t), parallel over (p,t,mblk).
// ---------------------------------------------------------------------------
__global__ __launch_bounds__(256) void tail_kernel(
    const short* __restrict__ z_all,
    const short* __restrict__ Tw1, const short* __restrict__ Tw2,
    const short* __restrict__ Dw1, const short* __restrict__ Dw2,
    const float* __restrict__ tb1, const float* __restrict__ tb2,
    const float* __restrict__ db1, const float* __restrict__ db2,
    float* __restrict__ prior_mean, float* __restrict__ prior_logvar,
    float* __restrict__ recons)
{
  const int tid  = threadIdx.x;
  const int wave = tid >> 6;
  const int lane = tid & 63;
  const int quad = lane >> 4;
  const int nl   = lane & 15;
  const int wg   = blockIdx.x;
  const int p    = wg >> 11;        // 0 = prior, 1 = decoder
  const int t    = (wg >> 2) & 511;
  const int mb   = wg & 3;          // 64-sample block

  const short* W1 = p ? Dw1 : Tw1;
  const short* W2 = p ? Dw2 : Tw2;
  const float* B1 = p ? db1 : tb1;
  const float* B2 = p ? db2 : tb2;

  __shared__ __align__(16) short u1[64][264];
  __shared__ float b1s[HID], b2s[OBS];

  b1s[tid] = B1[tid];
  if (tid < OBS) b2s[tid] = B2[tid];
  __syncthreads();

  const bool zzero = (p == 0 && t == 0);
  const int  tz    = p ? t : (t - 1);
  const short* zsrc = z_all + (((size_t)(zzero ? 0 : tz))*BB + mb*64)*LAT;

  // layer 1: M=64, N=256, K=64
  fvec4 acc1[4][4];
  for (int a = 0; a < 4; ++a) for (int b = 0; b < 4; ++b) acc1[a][b] = (fvec4)0.0f;
  for (int ks = 0; ks < 2; ++ks){
    bvec8 af[4];
    for (int mt = 0; mt < 4; ++mt){
      if (zzero) af[mt] = (bvec8)(short)0;
      else af[mt] = *(const bvec8*)(zsrc + (mt*16 + nl)*LAT + ks*32 + quad*8);
    }
    for (int nt = 0; nt < 4; ++nt){
      int n = (wave*4 + nt)*16 + nl;
      bvec8 bw = *(const bvec8*)(W1 + n*LAT + ks*32 + quad*8);
      for (int mt = 0; mt < 4; ++mt) acc1[mt][nt] = mfma16(af[mt], bw, acc1[mt][nt]);
    }
  }
  for (int nt = 0; nt < 4; ++nt){
    int n = (wave*4 + nt)*16 + nl;
    float bias = b1s[n];
    for (int mt = 0; mt < 4; ++mt)
      for (int r = 0; r < 4; ++r){
        float v = acc1[mt][nt][r] + bias;
        u1[mt*16 + quad*4 + r][n] = f2bf(v > 0.0f ? v : 0.0f);
      }
  }
  __syncthreads();

  // layer 2: M=64, N=128, K=256
  fvec4 acc2[4][2];
  for (int a = 0; a < 4; ++a) for (int b = 0; b < 2; ++b) acc2[a][b] = (fvec4)0.0f;
  for (int ks = 0; ks < 8; ++ks){
    bvec8 af[4];
    for (int mt = 0; mt < 4; ++mt)
      af[mt] = *(const bvec8*)(&u1[mt*16 + nl][ks*32 + quad*8]);
    for (int nt = 0; nt < 2; ++nt){
      int n = (wave*2 + nt)*16 + nl;
      bvec8 bw = *(const bvec8*)(W2 + n*HID + ks*32 + quad*8);
      for (int mt = 0; mt < 4; ++mt) acc2[mt][nt] = mfma16(af[mt], bw, acc2[mt][nt]);
    }
  }
  for (int nt = 0; nt < 2; ++nt){
    int n = (wave*2 + nt)*16 + nl;
    float bias = b2s[n];
    for (int mt = 0; mt < 4; ++mt)
      for (int r = 0; r < 4; ++r){
        int b = mb*64 + mt*16 + quad*4 + r;
        size_t row = (size_t)t*BB + b;
        float v = acc2[mt][nt][r] + bias;
        if (p) recons[row*OBS + n] = v;
        else if (n < LAT) prior_mean[row*LAT + n] = v;
        else              prior_logvar[row*LAT + (n - LAT)] = v;
      }
  }
}

extern "C" void kernel_launch(void* const* d_in, const int* in_sizes, int n_in,
                              void* d_out, int out_size, void* d_ws, size_t ws_size,
                              hipStream_t stream) {
  const float* x    = (const float*)d_in[0];
  const float* eps  = (const float*)d_in[1];
  const float* W_ih = (const float*)d_in[2];
  const float* W_hh = (const float*)d_in[3];
  const float* b_ih = (const float*)d_in[4];
  const float* b_hh = (const float*)d_in[5];
  const float* tW1  = (const float*)d_in[6];
  const float* tb1  = (const float*)d_in[7];
  const float* tW2  = (const float*)d_in[8];
  const float* tb2  = (const float*)d_in[9];
  const float* pW1  = (const float*)d_in[10];
  const float* pb1  = (const float*)d_in[11];
  const float* pW2  = (const float*)d_in[12];
  const float* pb2  = (const float*)d_in[13];
  const float* dW1  = (const float*)d_in[14];
  const float* db1  = (const float*)d_in[15];
  const float* dW2  = (const float*)d_in[16];
  const float* db2  = (const float*)d_in[17];

  float* out          = (float*)d_out;
  float* recons       = out;                 // 512*256*128
  float* prior_mean   = out + 16777216;      // 512*256*64
  float* prior_logvar = out + 25165824;
  float* post_mean    = out + 33554432;
  float* post_logvar  = out + 41943040;

  char* ws = (char*)d_ws;
  short* h_all = (short*)ws;                         // 512*256*256 bf16 = 67,108,864 B
  short* z_all = (short*)(ws + 67108864);            // 512*256*64  bf16 = 16,777,216 B
  short* wts   = (short*)(ws + 67108864 + 16777216);
  short* Pw1 = wts;                  // 81920
  short* Pw2 = Pw1 + 81920;          // 32768
  short* Tw1 = Pw2 + 32768;          // 16384
  short* Tw2 = Tw1 + 16384;          // 32768
  short* Dw1 = Tw2 + 32768;          // 16384
  short* Dw2 = Dw1 + 16384;          // 32768
  short* Wih_bf = Dw2 + 32768;       // 98304  (768 x 128)
  short* Whh_bf = Wih_bf + 98304;    // 196608 (768 x 256)

  // gx scratch: f16 [512*256][768] = 201,326,592 B == out_size exactly.
  // d_out is dead until zscan/tail (stream-ordered after gru_kernel reads gx).
  __half* gx = (__half*)d_out;

  cvt_kernel<<<(81920+255)/256, 256, 0, stream>>>(pW1, Pw1, 81920);
  cvt_kernel<<<(32768+255)/256, 256, 0, stream>>>(pW2, Pw2, 32768);
  cvt_kernel<<<(16384+255)/256, 256, 0, stream>>>(tW1, Tw1, 16384);
  cvt_kernel<<<(32768+255)/256, 256, 0, stream>>>(tW2, Tw2, 32768);
  cvt_kernel<<<(16384+255)/256, 256, 0, stream>>>(dW1, Dw1, 16384);
  cvt_kernel<<<(32768+255)/256, 256, 0, stream>>>(dW2, Dw2, 32768);
  cvt_kernel<<<(98304+255)/256, 256, 0, stream>>>(W_ih, Wih_bf, 98304);
  cvt_kernel<<<(196608+255)/256, 256, 0, stream>>>(W_hh, Whh_bf, 196608);

  gx_kernel<<<2048, 256, 0, stream>>>(x, Wih_bf, b_ih, b_hh, gx);
  gru_kernel<<<16, 512, 0, stream>>>(gx, Whh_bf, b_hh, h_all);
  zscan_kernel<<<16, 256, 0, stream>>>(h_all, eps, Pw1, Pw2, pb1, pb2,
                                       z_all, post_mean, post_logvar);
  tail_kernel<<<4096, 256, 0, stream>>>(z_all, Tw1, Tw2, Dw1, Dw2,
                                        tb1, tb2, db1, db2,
                                        prior_mean, prior_logvar, recons);
}

// Round 2
// 2439.946 us; speedup vs baseline: 2.5850x; 1.4413x over previous
//
#include <hip/hip_runtime.h>
#include <hip/hip_fp16.h>

#define TT 512
#define BB 256
#define OBS 128
#define LAT 64
#define HID 256

typedef short bvec8 __attribute__((ext_vector_type(8)));
typedef float fvec4 __attribute__((ext_vector_type(4)));

__device__ __forceinline__ short f2bf(float f){
  union { float f; unsigned u; } v; v.f = f;
  unsigned u = v.u;
  return (short)((u + 0x7FFFu + ((u >> 16) & 1u)) >> 16);
}

__device__ __forceinline__ bvec8 cvt8(const float* __restrict__ p){
  const float4* q = (const float4*)p;
  float4 lo = q[0], hi = q[1];
  bvec8 r;
  r[0] = f2bf(lo.x); r[1] = f2bf(lo.y); r[2] = f2bf(lo.z); r[3] = f2bf(lo.w);
  r[4] = f2bf(hi.x); r[5] = f2bf(hi.y); r[6] = f2bf(hi.z); r[7] = f2bf(hi.w);
  return r;
}

__device__ __forceinline__ fvec4 mfma16(bvec8 a, bvec8 b, fvec4 c){
  return __builtin_amdgcn_mfma_f32_16x16x32_bf16(a, b, c, 0, 0, 0);
}

// LDS-producer/consumer barrier that does NOT drain vmcnt: global loads/stores
// stay in flight across it (T4). ds_writes drained via lgkmcnt(0); the empty
// memory-clobber asm after s_barrier stops any LDS op hoisting across.
__device__ __forceinline__ void lds_barrier(){
  asm volatile("s_waitcnt lgkmcnt(0)" ::: "memory");
  __builtin_amdgcn_s_barrier();
  asm volatile("" ::: "memory");
}

__global__ void cvt_kernel(const float* __restrict__ src, short* __restrict__ dst, int n){
  int i = blockIdx.x * 256 + threadIdx.x;
  if (i < n) dst[i] = f2bf(src[i]);
}

// ---------------------------------------------------------------------------
// gx precompute: gx[t*B+b][gcol] = x[t][b] @ W_ih[gcol]^T + b_ih[gcol]
//                                  + (gcol < 2*HID ? b_hh[gcol] : 0)
// ---------------------------------------------------------------------------
__global__ __launch_bounds__(256) void gx_kernel(
    const float* __restrict__ x, const short* __restrict__ Wih_bf,
    const float* __restrict__ b_ih, const float* __restrict__ b_hh,
    __half* __restrict__ gx)
{
  const int tid  = threadIdx.x;
  const int wave = tid >> 6;
  const int lane = tid & 63;
  const int quad = lane >> 4;
  const int nl   = lane & 15;
  const int rowbase = blockIdx.x * 64 + wave * 16;

  bvec8 af[4];
#pragma unroll
  for (int ks = 0; ks < 4; ++ks)
    af[ks] = cvt8(x + (size_t)(rowbase + nl)*OBS + ks*32 + quad*8);

  for (int nt = 0; nt < 48; ++nt){
    const int n = nt*16 + nl;
    fvec4 acc = (fvec4)0.0f;
#pragma unroll
    for (int ks = 0; ks < 4; ++ks){
      bvec8 bw = *(const bvec8*)(Wih_bf + (size_t)n*OBS + ks*32 + quad*8);
      acc = mfma16(af[ks], bw, acc);
    }
    float bias = b_ih[n] + (n < 2*HID ? b_hh[n] : 0.0f);
#pragma unroll
    for (int r = 0; r < 4; ++r)
      gx[(size_t)(rowbase + quad*4 + r)*768 + n] = __float2half(acc[r] + bias);
  }
}

// ---------------------------------------------------------------------------
// u_pre precompute for zscan: u_pre[tb][n] = h[tb] @ pW1h^T + pb1  (f16)
// 1024 wgs x 256 thr; wave handles 32 rows x 256 cols.
// ---------------------------------------------------------------------------
__global__ __launch_bounds__(256) void upre_kernel(
    const short* __restrict__ h_all, const short* __restrict__ Pw1,
    const float* __restrict__ pb1, __half* __restrict__ u_pre)
{
  const int tid  = threadIdx.x;
  const int wave = tid >> 6;
  const int lane = tid & 63;
  const int quad = lane >> 4;
  const int nl   = lane & 15;
  const int rowbase = (blockIdx.x * 4 + wave) * 32;

  bvec8 af[2][8];
#pragma unroll
  for (int mt = 0; mt < 2; ++mt)
#pragma unroll
    for (int ks = 0; ks < 8; ++ks)
      af[mt][ks] = *(const bvec8*)(h_all + (size_t)(rowbase + mt*16 + nl)*HID + ks*32 + quad*8);

  for (int nt = 0; nt < 16; ++nt){
    const int n = nt*16 + nl;
    fvec4 acc[2];
    acc[0] = (fvec4)0.0f; acc[1] = (fvec4)0.0f;
#pragma unroll
    for (int ks = 0; ks < 8; ++ks){
      bvec8 bw = *(const bvec8*)(Pw1 + (size_t)n*320 + ks*32 + quad*8);
#pragma unroll
      for (int mt = 0; mt < 2; ++mt) acc[mt] = mfma16(af[mt][ks], bw, acc[mt]);
    }
    float bias = pb1[n];
#pragma unroll
    for (int mt = 0; mt < 2; ++mt)
#pragma unroll
      for (int r = 0; r < 4; ++r)
        u_pre[(size_t)(rowbase + mt*16 + quad*4 + r)*256 + n] = __float2half(acc[mt][r] + bias);
  }
}

// ---------------------------------------------------------------------------
// GRU scan: 16 wgs x 512 threads; wg g owns samples [16g, 16g+16).
// Wave w owns gate-columns [32w, 32w+32) of r,z,n.
// amdgpu_waves_per_eu(2,2): pins exactly 2 waves/SIMD -> 256-VGPR budget
// (launch_bounds(512,1) left the allocator at 128 -> per-step weight reload
// stalls; that was the whole 2250us). Register demand trimmed to ~235:
// r,z + 4 n-slices in VGPRs (160), 4 n-slices in LDS (64 KB).
// gx prefetched a full step early; raw lds_barrier keeps those loads and the
// h_all stores in flight across the barrier (no vmcnt(0) drain per step).
// ---------------------------------------------------------------------------
__attribute__((amdgpu_flat_work_group_size(512,512), amdgpu_waves_per_eu(2,2)))
__global__ void gru_kernel(
    const __half* __restrict__ gx,
    const short* __restrict__ Whh_bf,
    const float* __restrict__ b_hh,
    short* __restrict__ h_all)
{
  const int tid  = threadIdx.x;
  const int wave = tid >> 6;
  const int lane = tid & 63;
  const int quad = lane >> 4;
  const int nl   = lane & 15;
  const int b0   = blockIdx.x * 16;

  __shared__ __align__(16) short hA[2][16][264];
  __shared__ __align__(16) short WnL[4][2][8][512];  // [ks-4][nt][wave][lane*8]

  // ---- weights (B-frag layout: n=nl, k=quad*8+idx) ----
  bvec8 Whr[8][2], Whz[8][2], Whn[4][2];
  float bnh[2];
#pragma unroll
  for (int nt = 0; nt < 2; ++nt){
    const int j = wave*32 + nt*16 + nl;
#pragma unroll
    for (int ks = 0; ks < 8; ++ks){
      Whr[ks][nt] = *(const bvec8*)(Whh_bf + ((size_t)(0*HID + j))*HID + ks*32 + quad*8);
      Whz[ks][nt] = *(const bvec8*)(Whh_bf + ((size_t)(1*HID + j))*HID + ks*32 + quad*8);
    }
#pragma unroll
    for (int ks = 0; ks < 4; ++ks)
      Whn[ks][nt] = *(const bvec8*)(Whh_bf + ((size_t)(2*HID + j))*HID + ks*32 + quad*8);
#pragma unroll
    for (int ks = 4; ks < 8; ++ks){
      bvec8 w = *(const bvec8*)(Whh_bf + ((size_t)(2*HID + j))*HID + ks*32 + quad*8);
      *(bvec8*)&WnL[ks-4][nt][wave][lane*8] = w;
    }
    bnh[nt] = b_hh[2*HID + j];
  }

  float hreg[2][4];
#pragma unroll
  for (int nt = 0; nt < 2; ++nt)
#pragma unroll
    for (int r = 0; r < 4; ++r) hreg[nt][r] = 0.0f;

  // per-thread gx base: row = i*BB + b0 + quad*4 + r, col = g*HID + wave*32 + nt*16 + nl
  const __half* gbase = gx + ((size_t)(b0 + quad*4))*768 + wave*32 + nl;

  // preload step-0 gx
  __half gprz[16];   // [g(2)][nt(2)][r(4)] for NEXT consumed step
  __half gpn[8];     // n-gate for next consumed step
#pragma unroll
  for (int g = 0; g < 2; ++g)
#pragma unroll
    for (int nt = 0; nt < 2; ++nt)
#pragma unroll
      for (int r = 0; r < 4; ++r)
        gprz[(g*2+nt)*4+r] = gbase[(size_t)r*768 + g*HID + nt*16];
#pragma unroll
  for (int nt = 0; nt < 2; ++nt)
#pragma unroll
    for (int r = 0; r < 4; ++r)
      gpn[nt*4+r] = gbase[(size_t)r*768 + 2*HID + nt*16];

  const int orow = tid >> 5;    // 0..15
  const int oseg = tid & 31;    // 0..31
  lds_barrier();

  for (int i = 0; i < TT; ++i){
    // write out h_{i-1} (from LDS buffer finalized last step)
    if (i > 0){
      bvec8 v = *(const bvec8*)&hA[i&1][orow][oseg*8];
      *(bvec8*)(h_all + ((size_t)(i-1)*BB + b0 + orow)*HID + oseg*8) = v;
    }

    // acc init from prefetched gx (r,z); n-gate h-part starts at 0
    fvec4 ar[2], az[2], anh_[2];
#pragma unroll
    for (int nt = 0; nt < 2; ++nt){
#pragma unroll
      for (int r = 0; r < 4; ++r){
        ar[nt][r] = __half2float(gprz[(0*2+nt)*4+r]);
        az[nt][r] = __half2float(gprz[(1*2+nt)*4+r]);
      }
      anh_[nt] = (fvec4)0.0f;
    }

    // issue next-step r,z prefetch now (covered by MFMA + gate math)
    if (i + 1 < TT){
      const __half* gp = gbase + (size_t)(i+1)*BB*768;
#pragma unroll
      for (int g = 0; g < 2; ++g)
#pragma unroll
        for (int nt = 0; nt < 2; ++nt)
#pragma unroll
          for (int r = 0; r < 4; ++r)
            gprz[(g*2+nt)*4+r] = gp[(size_t)r*768 + g*HID + nt*16];
    }

    // h-part MFMAs (K=256)
    if (i > 0){
#pragma unroll
      for (int ks = 0; ks < 8; ++ks){
        bvec8 a = *(const bvec8*)&hA[i&1][nl][ks*32 + quad*8];
#pragma unroll
        for (int nt = 0; nt < 2; ++nt){
          ar[nt] = mfma16(a, Whr[ks][nt], ar[nt]);
          az[nt] = mfma16(a, Whz[ks][nt], az[nt]);
          if (ks < 4){
            anh_[nt] = mfma16(a, Whn[ks][nt], anh_[nt]);
          } else {
            bvec8 w = *(const bvec8*)&WnL[ks-4][nt][wave][lane*8];
            anh_[nt] = mfma16(a, w, anh_[nt]);
          }
        }
      }
    }

    // gate math (C-layout: m = quad*4+r, j = wave*32 + nt*16 + nl)
#pragma unroll
    for (int nt = 0; nt < 2; ++nt){
      const int j = wave*32 + nt*16 + nl;
#pragma unroll
      for (int r = 0; r < 4; ++r){
        float rg = 1.0f/(1.0f + __expf(-ar[nt][r]));
        float zg = 1.0f/(1.0f + __expf(-az[nt][r]));
        float nx = __half2float(gpn[nt*4+r]);
        float e2 = __expf(2.0f*(nx + rg*(anh_[nt][r] + bnh[nt])));
        float ng = 1.0f - 2.0f/(e2 + 1.0f);       // tanh
        float hn = (1.0f - zg)*ng + zg*hreg[nt][r];
        hreg[nt][r] = hn;
        hA[(i+1)&1][quad*4 + r][j] = f2bf(hn);
      }
    }

    // issue next-step n prefetch (covered by barrier + next out-store + MFMAs)
    if (i + 1 < TT){
      const __half* gp = gbase + (size_t)(i+1)*BB*768;
#pragma unroll
      for (int nt = 0; nt < 2; ++nt)
#pragma unroll
        for (int r = 0; r < 4; ++r)
          gpn[nt*4+r] = gp[(size_t)r*768 + 2*HID + nt*16];
    }

    lds_barrier();   // lgkmcnt-only: gx loads + h_all stores stay in flight
  }
  // epilogue: write h_{TT-1}  (TT even -> buffer 0)
  {
    bvec8 v = *(const bvec8*)&hA[TT&1][orow][oseg*8];
    *(bvec8*)(h_all + ((size_t)(TT-1)*BB + b0 + orow)*HID + oseg*8) = v;
  }
}

// ---------------------------------------------------------------------------
// z scan: 16 wgs x 256 threads; wg g owns samples [16g, 16g+16).
// h-part of layer 1 precomputed (u_pre, includes pb1). Serial loop keeps only
// the z-dependent work: 8 z-MFMAs + 16 stage-B MFMAs + z math.
// waves_per_eu(1,1): full register budget, no spills.
// ---------------------------------------------------------------------------
__attribute__((amdgpu_flat_work_group_size(256,256), amdgpu_waves_per_eu(1,1)))
__global__ void zscan_kernel(
    const __half* __restrict__ u_pre, const float* __restrict__ eps,
    const short* __restrict__ Pw1, const short* __restrict__ Pw2,
    const float* __restrict__ pb2,
    short* __restrict__ z_all,
    float* __restrict__ post_mean, float* __restrict__ post_logvar)
{
  const int tid  = threadIdx.x;
  const int wave = tid >> 6;
  const int lane = tid & 63;
  const int quad = lane >> 4;
  const int nl   = lane & 15;
  const int b0   = blockIdx.x * 16;

  __shared__ __align__(16) short zA[2][16][72];
  __shared__ __align__(16) short uA[16][264];
  __shared__ float postL[16][132];

  // weights (B-frag layout). pW1 z-part: k>=256 of [256][320].
  bvec8 W1z[2][4], W2[8][2];
#pragma unroll
  for (int nt = 0; nt < 4; ++nt){
    const int n = wave*64 + nt*16 + nl;
#pragma unroll
    for (int ks = 0; ks < 2; ++ks)
      W1z[ks][nt] = *(const bvec8*)(Pw1 + (size_t)n*320 + 256 + ks*32 + quad*8);
  }
#pragma unroll
  for (int nt = 0; nt < 2; ++nt){
    const int n = wave*32 + nt*16 + nl;
#pragma unroll
    for (int ks = 0; ks < 8; ++ks)
      W2[ks][nt] = *(const bvec8*)(Pw2 + (size_t)n*HID + ks*32 + quad*8);
  }

  // z-math constants per thread (4 latent cols each)
  const int zm  = tid >> 4;         // sample row 0..15
  const int zl  = (tid & 15) * 4;   // latent col base
  float4 pb2m = *(const float4*)(pb2 + zl);
  float4 pb2v = *(const float4*)(pb2 + 64 + zl);

  // prefetch u_pre + eps for step 0
  const __half* ubase = u_pre + ((size_t)(b0 + quad*4))*256 + wave*64 + nl;
  __half upf[16];
#pragma unroll
  for (int nt = 0; nt < 4; ++nt)
#pragma unroll
    for (int r = 0; r < 4; ++r)
      upf[nt*4+r] = ubase[(size_t)r*256 + nt*16];
  float4 ef = *(const float4*)(eps + ((size_t)0*BB + b0 + zm)*LAT + zl);

  for (int i = 0; i < TT; ++i){
    // ---- layer 1: au = u_pre + z_prev @ pW1z^T ----
    fvec4 au[4];
#pragma unroll
    for (int nt = 0; nt < 4; ++nt)
#pragma unroll
      for (int r = 0; r < 4; ++r)
        au[nt][r] = __half2float(upf[nt*4+r]);

    if (i + 1 < TT){
      const __half* up = ubase + (size_t)(i+1)*BB*256;
#pragma unroll
      for (int nt = 0; nt < 4; ++nt)
#pragma unroll
        for (int r = 0; r < 4; ++r)
          upf[nt*4+r] = up[(size_t)r*256 + nt*16];
    }

    if (i > 0){
#pragma unroll
      for (int ks = 0; ks < 2; ++ks){
        bvec8 a = *(const bvec8*)&zA[i&1][nl][ks*32 + quad*8];
#pragma unroll
        for (int nt = 0; nt < 4; ++nt) au[nt] = mfma16(a, W1z[ks][nt], au[nt]);
      }
    }
    // u = relu(au) -> uA   (pb1 already folded into u_pre)
#pragma unroll
    for (int nt = 0; nt < 4; ++nt){
      const int n = wave*64 + nt*16 + nl;
#pragma unroll
      for (int r = 0; r < 4; ++r){
        float u = au[nt][r];
        uA[quad*4 + r][n] = f2bf(u > 0.0f ? u : 0.0f);
      }
    }
    lds_barrier();

    // ---- stage B: post = u @ pW2^T ----
    fvec4 ap[2];
#pragma unroll
    for (int nt = 0; nt < 2; ++nt) ap[nt] = (fvec4)0.0f;
#pragma unroll
    for (int ks = 0; ks < 8; ++ks){
      bvec8 a = *(const bvec8*)&uA[nl][ks*32 + quad*8];
#pragma unroll
      for (int nt = 0; nt < 2; ++nt) ap[nt] = mfma16(a, W2[ks][nt], ap[nt]);
    }
#pragma unroll
    for (int nt = 0; nt < 2; ++nt){
      const int n = wave*32 + nt*16 + nl;
#pragma unroll
      for (int r = 0; r < 4; ++r) postL[quad*4 + r][n] = ap[nt][r];
    }
    lds_barrier();

    // ---- z math ----
    {
      float4 mean, lv;
      mean.x = postL[zm][zl+0] + pb2m.x;  lv.x = postL[zm][64+zl+0] + pb2v.x;
      mean.y = postL[zm][zl+1] + pb2m.y;  lv.y = postL[zm][64+zl+1] + pb2v.y;
      mean.z = postL[zm][zl+2] + pb2m.z;  lv.z = postL[zm][64+zl+2] + pb2v.z;
      mean.w = postL[zm][zl+3] + pb2m.w;  lv.w = postL[zm][64+zl+3] + pb2v.w;
      float z0 = mean.x + ef.x * __expf(0.5f*lv.x);
      float z1 = mean.y + ef.y * __expf(0.5f*lv.y);
      float z2 = mean.z + ef.z * __expf(0.5f*lv.z);
      float z3 = mean.w + ef.w * __expf(0.5f*lv.w);
      size_t orow = ((size_t)i*BB + b0 + zm)*LAT + zl;
      short4 zb; zb.x = f2bf(z0); zb.y = f2bf(z1); zb.z = f2bf(z2); zb.w = f2bf(z3);
      *(short4*)(z_all + orow) = zb;
      *(float4*)(post_mean + orow)   = mean;
      *(float4*)(post_logvar + orow) = lv;
      *(short4*)&zA[(i+1)&1][zm][zl] = zb;
      if (i + 1 < TT)
        ef = *(const float4*)(eps + ((size_t)(i+1)*BB + b0 + zm)*LAT + zl);
    }
    lds_barrier();
  }
}

// ---------------------------------------------------------------------------
// Tail: prior (from z_{t-1}) and decoder (from z_t), parallel over (p,t,mblk).
// ---------------------------------------------------------------------------
__global__ __launch_bounds__(256) void tail_kernel(
    const short* __restrict__ z_all,
    const short* __restrict__ Tw1, const short* __restrict__ Tw2,
    const short* __restrict__ Dw1, const short* __restrict__ Dw2,
    const float* __restrict__ tb1, const float* __restrict__ tb2,
    const float* __restrict__ db1, const float* __restrict__ db2,
    float* __restrict__ prior_mean, float* __restrict__ prior_logvar,
    float* __restrict__ recons)
{
  const int tid  = threadIdx.x;
  const int wave = tid >> 6;
  const int lane = tid & 63;
  const int quad = lane >> 4;
  const int nl   = lane & 15;
  const int wg   = blockIdx.x;
  const int p    = wg >> 11;        // 0 = prior, 1 = decoder
  const int t    = (wg >> 2) & 511;
  const int mb   = wg & 3;          // 64-sample block

  const short* W1 = p ? Dw1 : Tw1;
  const short* W2 = p ? Dw2 : Tw2;
  const float* B1 = p ? db1 : tb1;
  const float* B2 = p ? db2 : tb2;

  __shared__ __align__(16) short u1[64][264];
  __shared__ float b1s[HID], b2s[OBS];

  b1s[tid] = B1[tid];
  if (tid < OBS) b2s[tid] = B2[tid];
  __syncthreads();

  const bool zzero = (p == 0 && t == 0);
  const int  tz    = p ? t : (t - 1);
  const short* zsrc = z_all + (((size_t)(zzero ? 0 : tz))*BB + mb*64)*LAT;

  // layer 1: M=64, N=256, K=64
  fvec4 acc1[4][4];
  for (int a = 0; a < 4; ++a) for (int b = 0; b < 4; ++b) acc1[a][b] = (fvec4)0.0f;
  for (int ks = 0; ks < 2; ++ks){
    bvec8 af[4];
    for (int mt = 0; mt < 4; ++mt){
      if (zzero) af[mt] = (bvec8)(short)0;
      else af[mt] = *(const bvec8*)(zsrc + (mt*16 + nl)*LAT + ks*32 + quad*8);
    }
    for (int nt = 0; nt < 4; ++nt){
      int n = (wave*4 + nt)*16 + nl;
      bvec8 bw = *(const bvec8*)(W1 + n*LAT + ks*32 + quad*8);
      for (int mt = 0; mt < 4; ++mt) acc1[mt][nt] = mfma16(af[mt], bw, acc1[mt][nt]);
    }
  }
  for (int nt = 0; nt < 4; ++nt){
    int n = (wave*4 + nt)*16 + nl;
    float bias = b1s[n];
    for (int mt = 0; mt < 4; ++mt)
      for (int r = 0; r < 4; ++r){
        float v = acc1[mt][nt][r] + bias;
        u1[mt*16 + quad*4 + r][n] = f2bf(v > 0.0f ? v : 0.0f);
      }
  }
  __syncthreads();

  // layer 2: M=64, N=128, K=256
  fvec4 acc2[4][2];
  for (int a = 0; a < 4; ++a) for (int b = 0; b < 2; ++b) acc2[a][b] = (fvec4)0.0f;
  for (int ks = 0; ks < 8; ++ks){
    bvec8 af[4];
    for (int mt = 0; mt < 4; ++mt)
      af[mt] = *(const bvec8*)(&u1[mt*16 + nl][ks*32 + quad*8]);
    for (int nt = 0; nt < 2; ++nt){
      int n = (wave*2 + nt)*16 + nl;
      bvec8 bw = *(const bvec8*)(W2 + n*HID + ks*32 + quad*8);
      for (int mt = 0; mt < 4; ++mt) acc2[mt][nt] = mfma16(af[mt], bw, acc2[mt][nt]);
    }
  }
  for (int nt = 0; nt < 2; ++nt){
    int n = (wave*2 + nt)*16 + nl;
    float bias = b2s[n];
    for (int mt = 0; mt < 4; ++mt)
      for (int r = 0; r < 4; ++r){
        int b = mb*64 + mt*16 + quad*4 + r;
        size_t row = (size_t)t*BB + b;
        float v = acc2[mt][nt][r] + bias;
        if (p) recons[row*OBS + n] = v;
        else if (n < LAT) prior_mean[row*LAT + n] = v;
        else              prior_logvar[row*LAT + (n - LAT)] = v;
      }
  }
}

extern "C" void kernel_launch(void* const* d_in, const int* in_sizes, int n_in,
                              void* d_out, int out_size, void* d_ws, size_t ws_size,
                              hipStream_t stream) {
  const float* x    = (const float*)d_in[0];
  const float* eps  = (const float*)d_in[1];
  const float* W_ih = (const float*)d_in[2];
  const float* W_hh = (const float*)d_in[3];
  const float* b_ih = (const float*)d_in[4];
  const float* b_hh = (const float*)d_in[5];
  const float* tW1  = (const float*)d_in[6];
  const float* tb1  = (const float*)d_in[7];
  const float* tW2  = (const float*)d_in[8];
  const float* tb2  = (const float*)d_in[9];
  const float* pW1  = (const float*)d_in[10];
  const float* pb1  = (const float*)d_in[11];
  const float* pW2  = (const float*)d_in[12];
  const float* pb2  = (const float*)d_in[13];
  const float* dW1  = (const float*)d_in[14];
  const float* db1  = (const float*)d_in[15];
  const float* dW2  = (const float*)d_in[16];
  const float* db2  = (const float*)d_in[17];

  float* out          = (float*)d_out;
  float* recons       = out;                 // 512*256*128
  float* prior_mean   = out + 16777216;      // 512*256*64
  float* prior_logvar = out + 25165824;
  float* post_mean    = out + 33554432;
  float* post_logvar  = out + 41943040;

  char* ws = (char*)d_ws;
  short* h_all = (short*)ws;                         // 512*256*256 bf16 = 67,108,864 B
  short* z_all = (short*)(ws + 67108864);            // 512*256*64  bf16 = 16,777,216 B
  short* wts   = (short*)(ws + 67108864 + 16777216);
  short* Pw1 = wts;                  // 81920
  short* Pw2 = Pw1 + 81920;          // 32768
  short* Tw1 = Pw2 + 32768;          // 16384
  short* Tw2 = Tw1 + 16384;          // 32768
  short* Dw1 = Tw2 + 32768;          // 16384
  short* Dw2 = Dw1 + 16384;          // 32768
  short* Wih_bf = Dw2 + 32768;       // 98304  (768 x 128)
  short* Whh_bf = Wih_bf + 98304;    // 196608 (768 x 256)

  // gx scratch: f16 [512*256][768] = 201 MB == out_size exactly; dead after gru.
  // u_pre scratch: f16 [512*256][256] = 67 MB == recons region exactly; written
  // after gru (gx dead), read by zscan, overwritten by tail afterwards.
  __half* gx    = (__half*)d_out;
  __half* u_pre = (__half*)d_out;

  cvt_kernel<<<(81920+255)/256, 256, 0, stream>>>(pW1, Pw1, 81920);
  cvt_kernel<<<(32768+255)/256, 256, 0, stream>>>(pW2, Pw2, 32768);
  cvt_kernel<<<(16384+255)/256, 256, 0, stream>>>(tW1, Tw1, 16384);
  cvt_kernel<<<(32768+255)/256, 256, 0, stream>>>(tW2, Tw2, 32768);
  cvt_kernel<<<(16384+255)/256, 256, 0, stream>>>(dW1, Dw1, 16384);
  cvt_kernel<<<(32768+255)/256, 256, 0, stream>>>(dW2, Dw2, 32768);
  cvt_kernel<<<(98304+255)/256, 256, 0, stream>>>(W_ih, Wih_bf, 98304);
  cvt_kernel<<<(196608+255)/256, 256, 0, stream>>>(W_hh, Whh_bf, 196608);

  gx_kernel<<<2048, 256, 0, stream>>>(x, Wih_bf, b_ih, b_hh, gx);
  gru_kernel<<<16, 512, 0, stream>>>(gx, Whh_bf, b_hh, h_all);
  upre_kernel<<<1024, 256, 0, stream>>>(h_all, Pw1, pb1, u_pre);
  zscan_kernel<<<16, 256, 0, stream>>>(u_pre, eps, Pw1, Pw2, pb2,
                                       z_all, post_mean, post_logvar);
  tail_kernel<<<4096, 256, 0, stream>>>(z_all, Tw1, Tw2, Dw1, Dw2,
                                        tb1, tb2, db1, db2,
                                        prior_mean, prior_logvar, recons);
}

// Round 3
// 1796.495 us; speedup vs baseline: 3.5109x; 1.3582x over previous
//
#include <hip/hip_runtime.h>
#include <hip/hip_fp16.h>

#define TT 512
#define BB 256
#define OBS 128
#define LAT 64
#define HID 256

typedef short bvec8 __attribute__((ext_vector_type(8)));
typedef float fvec4 __attribute__((ext_vector_type(4)));
typedef _Float16 hvec8 __attribute__((ext_vector_type(8)));
typedef _Float16 hvec4 __attribute__((ext_vector_type(4)));

__device__ __forceinline__ short f2bf(float f){
  union { float f; unsigned u; } v; v.f = f;
  unsigned u = v.u;
  return (short)((u + 0x7FFFu + ((u >> 16) & 1u)) >> 16);
}

__device__ __forceinline__ bvec8 cvt8(const float* __restrict__ p){
  const float4* q = (const float4*)p;
  float4 lo = q[0], hi = q[1];
  bvec8 r;
  r[0] = f2bf(lo.x); r[1] = f2bf(lo.y); r[2] = f2bf(lo.z); r[3] = f2bf(lo.w);
  r[4] = f2bf(hi.x); r[5] = f2bf(hi.y); r[6] = f2bf(hi.z); r[7] = f2bf(hi.w);
  return r;
}

__device__ __forceinline__ fvec4 mfma16(bvec8 a, bvec8 b, fvec4 c){
  return __builtin_amdgcn_mfma_f32_16x16x32_bf16(a, b, c, 0, 0, 0);
}

__device__ __forceinline__ float fast_rcp(float x){ return __builtin_amdgcn_rcpf(x); }

// LDS-producer/consumer barrier that does NOT drain vmcnt: global loads/stores
// stay in flight across it. ds ops drained via lgkmcnt(0).
__device__ __forceinline__ void lds_barrier(){
  asm volatile("s_waitcnt lgkmcnt(0)" ::: "memory");
  __builtin_amdgcn_s_barrier();
  asm volatile("" ::: "memory");
}

__global__ void cvt_kernel(const float* __restrict__ src, short* __restrict__ dst, int n){
  int i = blockIdx.x * 256 + threadIdx.x;
  if (i < n) dst[i] = f2bf(src[i]);
}

// ---------------------------------------------------------------------------
// gx precompute, written CONSUMER-SWIZZLED so each gru thread's per-step gx
// is contiguous: gxrz[rowq][tid(512)][16 halfs: g(2)*8+nt(2)*4+r(4)],
//                gxn [rowq][tid(512)][8 halfs: nt*4+r],  rowq = t*16+wg.
// Biases folded: r,z get b_ih+b_hh; n gets b_ih only.
// ---------------------------------------------------------------------------
__global__ __launch_bounds__(256) void gx_kernel(
    const float* __restrict__ x, const short* __restrict__ Wih_bf,
    const float* __restrict__ b_ih, const float* __restrict__ b_hh,
    __half* __restrict__ gxrz, __half* __restrict__ gxn)
{
  const int tid  = threadIdx.x;
  const int wave = tid >> 6;
  const int lane = tid & 63;
  const int quad = lane >> 4;
  const int nl   = lane & 15;
  const int rowbase = blockIdx.x * 64 + wave * 16;   // multiple of 16
  const int rowq    = rowbase >> 4;                  // = t*16 + wg

  bvec8 af[4];
#pragma unroll
  for (int ks = 0; ks < 4; ++ks)
    af[ks] = cvt8(x + (size_t)(rowbase + nl)*OBS + ks*32 + quad*8);

  for (int nt48 = 0; nt48 < 48; ++nt48){
    const int n = nt48*16 + nl;
    fvec4 acc = (fvec4)0.0f;
#pragma unroll
    for (int ks = 0; ks < 4; ++ks){
      bvec8 bw = *(const bvec8*)(Wih_bf + (size_t)n*OBS + ks*32 + quad*8);
      acc = mfma16(af[ks], bw, acc);
    }
    const int g   = nt48 >> 4;            // 0=r, 1=z, 2=n
    float bias = b_ih[n] + (g < 2 ? b_hh[n] : 0.0f);
    hvec4 s;
#pragma unroll
    for (int r = 0; r < 4; ++r) s[r] = (_Float16)(acc[r] + bias);
    const int wc  = (nt48 & 15) >> 1;     // consumer wave
    const int ntc = nt48 & 1;             // consumer nt
    const size_t tb = (size_t)rowq*512 + wc*64 + quad*16 + nl;
    if (g < 2) *(hvec4*)(gxrz + tb*16 + g*8 + ntc*4) = s;
    else       *(hvec4*)(gxn  + tb*8  + ntc*4)       = s;
  }
}

// ---------------------------------------------------------------------------
// u_pre for zscan (512-thread consumer), swizzled: usw[rowq][tid(512)][8 halfs:
// nt(2)*4+r(4)], consumer n = wave*32 + nt*16 + nl. pb1 folded in.
// ---------------------------------------------------------------------------
__global__ __launch_bounds__(256) void upre_kernel(
    const short* __restrict__ h_all, const short* __restrict__ Pw1,
    const float* __restrict__ pb1, __half* __restrict__ usw)
{
  const int tid  = threadIdx.x;
  const int wave = tid >> 6;
  const int lane = tid & 63;
  const int quad = lane >> 4;
  const int nl   = lane & 15;
  const int rowbase = (blockIdx.x * 4 + wave) * 32;
  const int rowq0   = rowbase >> 4;

  bvec8 af[2][8];
#pragma unroll
  for (int mt = 0; mt < 2; ++mt)
#pragma unroll
    for (int ks = 0; ks < 8; ++ks)
      af[mt][ks] = *(const bvec8*)(h_all + (size_t)(rowbase + mt*16 + nl)*HID + ks*32 + quad*8);

  for (int nt16 = 0; nt16 < 16; ++nt16){
    const int n = nt16*16 + nl;
    fvec4 acc[2];
    acc[0] = (fvec4)0.0f; acc[1] = (fvec4)0.0f;
#pragma unroll
    for (int ks = 0; ks < 8; ++ks){
      bvec8 bw = *(const bvec8*)(Pw1 + (size_t)n*320 + ks*32 + quad*8);
#pragma unroll
      for (int mt = 0; mt < 2; ++mt) acc[mt] = mfma16(af[mt][ks], bw, acc[mt]);
    }
    float bias = pb1[n];
    const int wc  = nt16 >> 1;
    const int ntc = nt16 & 1;
#pragma unroll
    for (int mt = 0; mt < 2; ++mt){
      hvec4 s;
#pragma unroll
      for (int r = 0; r < 4; ++r) s[r] = (_Float16)(acc[mt][r] + bias);
      const size_t tb = (size_t)(rowq0 + mt)*512 + wc*64 + quad*16 + nl;
      *(hvec4*)(usw + tb*8 + ntc*4) = s;
    }
  }
}

// ---------------------------------------------------------------------------
// GRU scan: 16 wgs x 512 threads; wg g owns samples [16g, 16g+16).
// Wave w owns gate-columns [32w, 32w+32) of r,z,n.
// Weights: r,z + 4 n-slices in regs (160 VGPR), 4 n-slices in LDS (64 KB).
// gx loads are now 3 x dwordx4 per thread per step (pre-swizzled layout),
// replacing 24 scalar 2B loads — drops reg demand to ~230 < 256 budget and
// makes the one-step-ahead prefetch schedulable. rcp-based sigmoid/tanh.
// ---------------------------------------------------------------------------
__attribute__((amdgpu_flat_work_group_size(512,512), amdgpu_waves_per_eu(2,2)))
__global__ void gru_kernel(
    const __half* __restrict__ gxrz, const __half* __restrict__ gxn,
    const short* __restrict__ Whh_bf,
    const float* __restrict__ b_hh,
    short* __restrict__ h_all)
{
  const int tid  = threadIdx.x;
  const int wave = tid >> 6;
  const int lane = tid & 63;
  const int quad = lane >> 4;
  const int nl   = lane & 15;
  const int b0   = blockIdx.x * 16;

  __shared__ __align__(16) short hA[2][16][264];
  __shared__ __align__(16) short WnL[4][2][8][512];  // [ks-4][nt][wave][lane*8]

  // ---- weights (B-frag layout: n=nl, k=quad*8+idx) ----
  bvec8 Whr[8][2], Whz[8][2], Whn[4][2];
  float bnh[2];
#pragma unroll
  for (int nt = 0; nt < 2; ++nt){
    const int j = wave*32 + nt*16 + nl;
#pragma unroll
    for (int ks = 0; ks < 8; ++ks){
      Whr[ks][nt] = *(const bvec8*)(Whh_bf + ((size_t)(0*HID + j))*HID + ks*32 + quad*8);
      Whz[ks][nt] = *(const bvec8*)(Whh_bf + ((size_t)(1*HID + j))*HID + ks*32 + quad*8);
    }
#pragma unroll
    for (int ks = 0; ks < 4; ++ks)
      Whn[ks][nt] = *(const bvec8*)(Whh_bf + ((size_t)(2*HID + j))*HID + ks*32 + quad*8);
#pragma unroll
    for (int ks = 4; ks < 8; ++ks){
      bvec8 w = *(const bvec8*)(Whh_bf + ((size_t)(2*HID + j))*HID + ks*32 + quad*8);
      *(bvec8*)&WnL[ks-4][nt][wave][lane*8] = w;
    }
    bnh[nt] = b_hh[2*HID + j];
  }

  float hreg[2][4];
#pragma unroll
  for (int nt = 0; nt < 2; ++nt)
#pragma unroll
    for (int r = 0; r < 4; ++r) hreg[nt][r] = 0.0f;

  // swizzled gx bases (per thread); step strides in halfs
  const __half* grzp = gxrz + ((size_t)blockIdx.x*512 + tid)*16;
  const __half* gnp  = gxn  + ((size_t)blockIdx.x*512 + tid)*8;
  const size_t RZSTEP = (size_t)16*512*16;   // 131072
  const size_t NSTEP  = (size_t)16*512*8;    // 65536

  hvec8 grzA = *(const hvec8*)grzp;          // r-gate [nt*4+r]
  hvec8 grzB = *(const hvec8*)(grzp + 8);    // z-gate [nt*4+r]
  hvec8 gnA  = *(const hvec8*)gnp;           // n-gate [nt*4+r]

  const int orow = tid >> 5;    // 0..15
  const int oseg = tid & 31;    // 0..31
  lds_barrier();

  for (int i = 0; i < TT; ++i){
    // write out h_{i-1} (from LDS buffer finalized last step)
    if (i > 0){
      bvec8 v = *(const bvec8*)&hA[i&1][orow][oseg*8];
      *(bvec8*)(h_all + ((size_t)(i-1)*BB + b0 + orow)*HID + oseg*8) = v;
    }

    // acc init from prefetched gx (r,z); n-gate h-part starts at 0
    fvec4 ar[2], az[2], anh_[2];
#pragma unroll
    for (int nt = 0; nt < 2; ++nt){
#pragma unroll
      for (int r = 0; r < 4; ++r){
        ar[nt][r] = (float)grzA[nt*4+r];
        az[nt][r] = (float)grzB[nt*4+r];
      }
      anh_[nt] = (fvec4)0.0f;
    }

    // issue next-step r,z prefetch now (covered by MFMA + gate math)
    if (i + 1 < TT){
      const __half* p = grzp + (size_t)(i+1)*RZSTEP;
      grzA = *(const hvec8*)p;
      grzB = *(const hvec8*)(p + 8);
    }

    // h-part MFMAs (K=256)
    if (i > 0){
#pragma unroll
      for (int ks = 0; ks < 8; ++ks){
        bvec8 a = *(const bvec8*)&hA[i&1][nl][ks*32 + quad*8];
#pragma unroll
        for (int nt = 0; nt < 2; ++nt){
          ar[nt] = mfma16(a, Whr[ks][nt], ar[nt]);
          az[nt] = mfma16(a, Whz[ks][nt], az[nt]);
          if (ks < 4){
            anh_[nt] = mfma16(a, Whn[ks][nt], anh_[nt]);
          } else {
            bvec8 w = *(const bvec8*)&WnL[ks-4][nt][wave][lane*8];
            anh_[nt] = mfma16(a, w, anh_[nt]);
          }
        }
      }
    }

    // gate math (C-layout: m = quad*4+r, j = wave*32 + nt*16 + nl)
#pragma unroll
    for (int nt = 0; nt < 2; ++nt){
      const int j = wave*32 + nt*16 + nl;
#pragma unroll
      for (int r = 0; r < 4; ++r){
        float rg = fast_rcp(1.0f + __expf(-ar[nt][r]));
        float zg = fast_rcp(1.0f + __expf(-az[nt][r]));
        float nx = (float)gnA[nt*4+r];
        float e2 = __expf(2.0f*(nx + rg*(anh_[nt][r] + bnh[nt])));
        float ng = 1.0f - 2.0f*fast_rcp(e2 + 1.0f);       // tanh
        float hn = (1.0f - zg)*ng + zg*hreg[nt][r];
        hreg[nt][r] = hn;
        hA[(i+1)&1][quad*4 + r][j] = f2bf(hn);
      }
    }

    // issue next-step n prefetch (after its last use this step)
    if (i + 1 < TT)
      gnA = *(const hvec8*)(gnp + (size_t)(i+1)*NSTEP);

    lds_barrier();   // lgkmcnt-only: gx loads + h_all stores stay in flight
  }
  // epilogue: write h_{TT-1}  (TT even -> buffer 0)
  {
    bvec8 v = *(const bvec8*)&hA[TT&1][orow][oseg*8];
    *(bvec8*)(h_all + ((size_t)(TT-1)*BB + b0 + orow)*HID + oseg*8) = v;
  }
}

// ---------------------------------------------------------------------------
// z scan: 16 wgs x 512 threads (2 waves/SIMD). Wave w owns layer-1 columns
// [32w,32w+32) and stage-B column block [16w,16w+16). u_pre swizzled+vector.
// ---------------------------------------------------------------------------
__global__ __launch_bounds__(512) void zscan_kernel(
    const __half* __restrict__ usw, const float* __restrict__ eps,
    const short* __restrict__ Pw1, const short* __restrict__ Pw2,
    const float* __restrict__ pb2,
    short* __restrict__ z_all,
    float* __restrict__ post_mean, float* __restrict__ post_logvar)
{
  const int tid  = threadIdx.x;
  const int wave = tid >> 6;
  const int lane = tid & 63;
  const int quad = lane >> 4;
  const int nl   = lane & 15;
  const int b0   = blockIdx.x * 16;

  __shared__ __align__(16) short zA[2][16][72];
  __shared__ __align__(16) short uA[16][264];
  __shared__ float postL[16][132];

  // layer-1 z-part weights: n = wave*32 + nt*16 + nl (k 256..320 of pW1)
  bvec8 W1z[2][2];
#pragma unroll
  for (int nt = 0; nt < 2; ++nt){
    const int n = wave*32 + nt*16 + nl;
#pragma unroll
    for (int ks = 0; ks < 2; ++ks)
      W1z[ks][nt] = *(const bvec8*)(Pw1 + (size_t)n*320 + 256 + ks*32 + quad*8);
  }
  // stage-B weights: n2 = wave*16 + nl
  bvec8 W2[8];
  {
    const int n2 = wave*16 + nl;
#pragma unroll
    for (int ks = 0; ks < 8; ++ks)
      W2[ks] = *(const bvec8*)(Pw2 + (size_t)n2*HID + ks*32 + quad*8);
  }

  // z-math: each thread owns 2 latent cols of one sample row
  const int zm  = tid >> 5;         // sample row 0..15
  const int zl  = (tid & 31) * 2;   // latent col base (0..62)
  float2 pb2m = *(const float2*)(pb2 + zl);
  float2 pb2v = *(const float2*)(pb2 + 64 + zl);

  const __half* ub = usw + ((size_t)blockIdx.x*512 + tid)*8;
  const size_t USTEP = (size_t)16*512*8;   // 65536
  hvec8 upf = *(const hvec8*)ub;
  float2 ef = *(const float2*)(eps + ((size_t)0*BB + b0 + zm)*LAT + zl);

  for (int i = 0; i < TT; ++i){
    // ---- layer 1: au = u_pre + z_prev @ pW1z^T ----
    fvec4 au[2];
#pragma unroll
    for (int nt = 0; nt < 2; ++nt)
#pragma unroll
      for (int r = 0; r < 4; ++r)
        au[nt][r] = (float)upf[nt*4+r];

    if (i + 1 < TT)
      upf = *(const hvec8*)(ub + (size_t)(i+1)*USTEP);

    if (i > 0){
#pragma unroll
      for (int ks = 0; ks < 2; ++ks){
        bvec8 a = *(const bvec8*)&zA[i&1][nl][ks*32 + quad*8];
#pragma unroll
        for (int nt = 0; nt < 2; ++nt) au[nt] = mfma16(a, W1z[ks][nt], au[nt]);
      }
    }
    // u = relu(au) -> uA   (pb1 folded into u_pre)
#pragma unroll
    for (int nt = 0; nt < 2; ++nt){
      const int n = wave*32 + nt*16 + nl;
#pragma unroll
      for (int r = 0; r < 4; ++r){
        float u = au[nt][r];
        uA[quad*4 + r][n] = f2bf(u > 0.0f ? u : 0.0f);
      }
    }
    lds_barrier();

    // ---- stage B: post = u @ pW2^T ----
    fvec4 ap = (fvec4)0.0f;
#pragma unroll
    for (int ks = 0; ks < 8; ++ks){
      bvec8 a = *(const bvec8*)&uA[nl][ks*32 + quad*8];
      ap = mfma16(a, W2[ks], ap);
    }
    {
      const int n2 = wave*16 + nl;
#pragma unroll
      for (int r = 0; r < 4; ++r) postL[quad*4 + r][n2] = ap[r];
    }
    lds_barrier();

    // ---- z math (2 cols/thread) ----
    {
      float m0 = postL[zm][zl+0] + pb2m.x, lv0 = postL[zm][64+zl+0] + pb2v.x;
      float m1 = postL[zm][zl+1] + pb2m.y, lv1 = postL[zm][64+zl+1] + pb2v.y;
      float z0 = m0 + ef.x * __expf(0.5f*lv0);
      float z1 = m1 + ef.y * __expf(0.5f*lv1);
      size_t orow = ((size_t)i*BB + b0 + zm)*LAT + zl;
      short2 zb; zb.x = f2bf(z0); zb.y = f2bf(z1);
      *(short2*)(z_all + orow) = zb;
      float2 mm; mm.x = m0; mm.y = m1;
      float2 vv; vv.x = lv0; vv.y = lv1;
      *(float2*)(post_mean + orow)   = mm;
      *(float2*)(post_logvar + orow) = vv;
      *(short2*)&zA[(i+1)&1][zm][zl] = zb;
      if (i + 1 < TT)
        ef = *(const float2*)(eps + ((size_t)(i+1)*BB + b0 + zm)*LAT + zl);
    }
    lds_barrier();
  }
}

// ---------------------------------------------------------------------------
// Tail: prior (from z_{t-1}) and decoder (from z_t), parallel over (p,t,mblk).
// ---------------------------------------------------------------------------
__global__ __launch_bounds__(256) void tail_kernel(
    const short* __restrict__ z_all,
    const short* __restrict__ Tw1, const short* __restrict__ Tw2,
    const short* __restrict__ Dw1, const short* __restrict__ Dw2,
    const float* __restrict__ tb1, const float* __restrict__ tb2,
    const float* __restrict__ db1, const float* __restrict__ db2,
    float* __restrict__ prior_mean, float* __restrict__ prior_logvar,
    float* __restrict__ recons)
{
  const int tid  = threadIdx.x;
  const int wave = tid >> 6;
  const int lane = tid & 63;
  const int quad = lane >> 4;
  const int nl   = lane & 15;
  const int wg   = blockIdx.x;
  const int p    = wg >> 11;        // 0 = prior, 1 = decoder
  const int t    = (wg >> 2) & 511;
  const int mb   = wg & 3;          // 64-sample block

  const short* W1 = p ? Dw1 : Tw1;
  const short* W2 = p ? Dw2 : Tw2;
  const float* B1 = p ? db1 : tb1;
  const float* B2 = p ? db2 : tb2;

  __shared__ __align__(16) short u1[64][264];
  __shared__ float b1s[HID], b2s[OBS];

  b1s[tid] = B1[tid];
  if (tid < OBS) b2s[tid] = B2[tid];
  __syncthreads();

  const bool zzero = (p == 0 && t == 0);
  const int  tz    = p ? t : (t - 1);
  const short* zsrc = z_all + (((size_t)(zzero ? 0 : tz))*BB + mb*64)*LAT;

  // layer 1: M=64, N=256, K=64
  fvec4 acc1[4][4];
  for (int a = 0; a < 4; ++a) for (int b = 0; b < 4; ++b) acc1[a][b] = (fvec4)0.0f;
  for (int ks = 0; ks < 2; ++ks){
    bvec8 af[4];
    for (int mt = 0; mt < 4; ++mt){
      if (zzero) af[mt] = (bvec8)(short)0;
      else af[mt] = *(const bvec8*)(zsrc + (mt*16 + nl)*LAT + ks*32 + quad*8);
    }
    for (int nt = 0; nt < 4; ++nt){
      int n = (wave*4 + nt)*16 + nl;
      bvec8 bw = *(const bvec8*)(W1 + n*LAT + ks*32 + quad*8);
      for (int mt = 0; mt < 4; ++mt) acc1[mt][nt] = mfma16(af[mt], bw, acc1[mt][nt]);
    }
  }
  for (int nt = 0; nt < 4; ++nt){
    int n = (wave*4 + nt)*16 + nl;
    float bias = b1s[n];
    for (int mt = 0; mt < 4; ++mt)
      for (int r = 0; r < 4; ++r){
        float v = acc1[mt][nt][r] + bias;
        u1[mt*16 + quad*4 + r][n] = f2bf(v > 0.0f ? v : 0.0f);
      }
  }
  __syncthreads();

  // layer 2: M=64, N=128, K=256
  fvec4 acc2[4][2];
  for (int a = 0; a < 4; ++a) for (int b = 0; b < 2; ++b) acc2[a][b] = (fvec4)0.0f;
  for (int ks = 0; ks < 8; ++ks){
    bvec8 af[4];
    for (int mt = 0; mt < 4; ++mt)
      af[mt] = *(const bvec8*)(&u1[mt*16 + nl][ks*32 + quad*8]);
    for (int nt = 0; nt < 2; ++nt){
      int n = (wave*2 + nt)*16 + nl;
      bvec8 bw = *(const bvec8*)(W2 + n*HID + ks*32 + quad*8);
      for (int mt = 0; mt < 4; ++mt) acc2[mt][nt] = mfma16(af[mt], bw, acc2[mt][nt]);
    }
  }
  for (int nt = 0; nt < 2; ++nt){
    int n = (wave*2 + nt)*16 + nl;
    float bias = b2s[n];
    for (int mt = 0; mt < 4; ++mt)
      for (int r = 0; r < 4; ++r){
        int b = mb*64 + mt*16 + quad*4 + r;
        size_t row = (size_t)t*BB + b;
        float v = acc2[mt][nt][r] + bias;
        if (p) recons[row*OBS + n] = v;
        else if (n < LAT) prior_mean[row*LAT + n] = v;
        else              prior_logvar[row*LAT + (n - LAT)] = v;
      }
  }
}

extern "C" void kernel_launch(void* const* d_in, const int* in_sizes, int n_in,
                              void* d_out, int out_size, void* d_ws, size_t ws_size,
                              hipStream_t stream) {
  const float* x    = (const float*)d_in[0];
  const float* eps  = (const float*)d_in[1];
  const float* W_ih = (const float*)d_in[2];
  const float* W_hh = (const float*)d_in[3];
  const float* b_ih = (const float*)d_in[4];
  const float* b_hh = (const float*)d_in[5];
  const float* tW1  = (const float*)d_in[6];
  const float* tb1  = (const float*)d_in[7];
  const float* tW2  = (const float*)d_in[8];
  const float* tb2  = (const float*)d_in[9];
  const float* pW1  = (const float*)d_in[10];
  const float* pb1  = (const float*)d_in[11];
  const float* pW2  = (const float*)d_in[12];
  const float* pb2  = (const float*)d_in[13];
  const float* dW1  = (const float*)d_in[14];
  const float* db1  = (const float*)d_in[15];
  const float* dW2  = (const float*)d_in[16];
  const float* db2  = (const float*)d_in[17];

  float* out          = (float*)d_out;
  float* recons       = out;                 // 512*256*128
  float* prior_mean   = out + 16777216;      // 512*256*64
  float* prior_logvar = out + 25165824;
  float* post_mean    = out + 33554432;
  float* post_logvar  = out + 41943040;

  char* ws = (char*)d_ws;
  short* h_all = (short*)ws;                         // 512*256*256 bf16 = 67,108,864 B
  short* z_all = (short*)(ws + 67108864);            // 512*256*64  bf16 = 16,777,216 B
  short* wts   = (short*)(ws + 67108864 + 16777216);
  short* Pw1 = wts;                  // 81920
  short* Pw2 = Pw1 + 81920;          // 32768
  short* Tw1 = Pw2 + 32768;          // 16384
  short* Tw2 = Tw1 + 16384;          // 32768
  short* Dw1 = Tw2 + 32768;          // 16384
  short* Dw2 = Dw1 + 16384;          // 32768
  short* Wih_bf = Dw2 + 32768;       // 98304  (768 x 128)
  short* Whh_bf = Wih_bf + 98304;    // 196608 (768 x 256)

  // gx scratch (swizzled): gxrz 134,217,728 B + gxn 67,108,864 B = 201,326,592 B
  //   == out_size exactly; dead after gru_kernel.
  // usw scratch (swizzled u_pre): 67,108,864 B == recons region exactly; written
  //   after gru (gx dead), read by zscan, overwritten by tail afterwards.
  __half* gxrz = (__half*)d_out;
  __half* gxn  = (__half*)d_out + 67108864;   // +134,217,728 B
  __half* usw  = (__half*)d_out;

  cvt_kernel<<<(81920+255)/256, 256, 0, stream>>>(pW1, Pw1, 81920);
  cvt_kernel<<<(32768+255)/256, 256, 0, stream>>>(pW2, Pw2, 32768);
  cvt_kernel<<<(16384+255)/256, 256, 0, stream>>>(tW1, Tw1, 16384);
  cvt_kernel<<<(32768+255)/256, 256, 0, stream>>>(tW2, Tw2, 32768);
  cvt_kernel<<<(16384+255)/256, 256, 0, stream>>>(dW1, Dw1, 16384);
  cvt_kernel<<<(32768+255)/256, 256, 0, stream>>>(dW2, Dw2, 32768);
  cvt_kernel<<<(98304+255)/256, 256, 0, stream>>>(W_ih, Wih_bf, 98304);
  cvt_kernel<<<(196608+255)/256, 256, 0, stream>>>(W_hh, Whh_bf, 196608);

  gx_kernel<<<2048, 256, 0, stream>>>(x, Wih_bf, b_ih, b_hh, gxrz, gxn);
  gru_kernel<<<16, 512, 0, stream>>>(gxrz, gxn, Whh_bf, b_hh, h_all);
  upre_kernel<<<1024, 256, 0, stream>>>(h_all, Pw1, pb1, usw);
  zscan_kernel<<<16, 512, 0, stream>>>(usw, eps, Pw1, Pw2, pb2,
                                       z_all, post_mean, post_logvar);
  tail_kernel<<<4096, 256, 0, stream>>>(z_all, Tw1, Tw2, Dw1, Dw2,
                                        tb1, tb2, db1, db2,
                                        prior_mean, prior_logvar, recons);
}